// Round 4
// baseline (396.479 us; speedup 1.0000x reference)
//
#include <hip/hip_runtime.h>
#include <math.h>

#define B_ 4
#define S_ 4096
#define D_ 768
#define DH 384              // per-block d-half
#define U_ 64
#define TQ 64
#define TK 32
#define NT (S_ / TK)
#define XT_TILE (TK * D_)   // 24576 elems (48KB) per key-tile in global, fragment-ordered
#define XT_HALF (TK * DH)   // 12288 elems (24KB) staged per block
#define K_TILE  (TK * U_)   // 2048 elems (4KB)
#define Q_TILE  (TQ * U_)   // 4096 elems (8KB)
#define NTHR 384

typedef __attribute__((ext_vector_type(8))) short short8;
typedef __attribute__((ext_vector_type(4))) float f32x4;
typedef __attribute__((ext_vector_type(16))) float f32x16;

__device__ __forceinline__ unsigned short f2bf(float f) {
    unsigned int x = __float_as_uint(f);
    unsigned int r = (x + 0x7fffu + ((x >> 16) & 1u)) >> 16;
    return (unsigned short)r;
}

#define GLOAD16(gsrc, ldst)                                                             \
    __builtin_amdgcn_global_load_lds(                                                   \
        (const __attribute__((address_space(1))) unsigned int*)(const void*)(gsrc),     \
        (__attribute__((address_space(3))) unsigned int*)(void*)(ldst), 16, 0, 0)

#define BARRIER()                                   \
    {                                               \
        __builtin_amdgcn_sched_barrier(0);          \
        asm volatile("s_barrier" ::: "memory");     \
        __builtin_amdgcn_sched_barrier(0);          \
    }

// ---------------- kernel 1: decode mask (auto-detect bool8 vs int32) ----------------
__global__ __launch_bounds__(256) void decode_mask_k(const unsigned char* __restrict__ mraw,
                                                     float* __restrict__ maskf) {
    int base = threadIdx.x * 4;
    int bad = (mraw[base + 1] | mraw[base + 2] | mraw[base + 3]) != 0;
    int isbyte = __syncthreads_or(bad);
    int i = blockIdx.x * 256 + threadIdx.x;
    if (i < B_ * S_) {
        int v = isbyte ? (int)mraw[i] : ((const int*)mraw)[i];
        maskf[i] = (v != 0) ? 1.0f : 0.0f;
    }
}

// ---------------- kernel 2: q/k projection -> bf16, MFMA-fragment-ordered ----------------
__global__ __launch_bounds__(256) void proj_qk_k(const float* __restrict__ x,
                                                 const float* __restrict__ Wq,
                                                 const float* __restrict__ Wk,
                                                 unsigned short* __restrict__ qg,
                                                 unsigned short* __restrict__ kg) {
    __shared__ float xs[16][D_];
    const int rbase = blockIdx.x * 16;
    const float4* xsrc = (const float4*)(x + (size_t)rbase * D_);
    float4* xdst = (float4*)&xs[0][0];
    for (int i = threadIdx.x; i < 16 * D_ / 4; i += 256) xdst[i] = xsrc[i];
    __syncthreads();

    const int c  = threadIdx.x & 127;
    const int rg = threadIdx.x >> 7;
    const float* __restrict__ W = (c < 64) ? Wq : Wk;
    const int u = c & 63;

    float acc[8] = {0.f, 0.f, 0.f, 0.f, 0.f, 0.f, 0.f, 0.f};
    #pragma unroll 4
    for (int d = 0; d < D_; ++d) {
        const float wv = W[d * U_ + u];
        #pragma unroll
        for (int r = 0; r < 8; ++r) acc[r] = fmaf(xs[rg * 8 + r][d], wv, acc[r]);
    }

    const int h  = u >> 5;
    const int lg = (u >> 3) & 3;
    const int e  = u & 7;
    const int row0 = rbase + rg * 8;
    if (c < 64) {
        unsigned short* dstq = qg + (size_t)(row0 >> 6) * Q_TILE
            + ((((((row0 >> 4) & 3) * 2 + h) * 4 + lg) * 16) + (row0 & 15)) * 8 + e;
        #pragma unroll
        for (int r = 0; r < 8; ++r) dstq[r * 8] = f2bf(acc[r]);
    } else {
        unsigned short* dstk = kg + (size_t)(row0 >> 5) * K_TILE
            + (((h * 2 + ((row0 >> 4) & 1)) * 4 + lg) * 16 + (row0 & 15)) * 8 + e;
        #pragma unroll
        for (int r = 0; r < 8; ++r) dstk[r * 8] = f2bf(acc[r]);
    }
}

// ---------------- kernel 3: x -> xT B-fragments, per (b, key-tile) ----------------
// chunk c in [0,3072): kw=c/1536, db=(c>>6)%24, kh=(c>>5)&1, col=c&31
__global__ __launch_bounds__(512) void xpose_k(const float* __restrict__ x,
                                               unsigned short* __restrict__ xTg) {
    __shared__ float xs[TK][D_ + 4];
    const int tid = threadIdx.x;
    const int bt  = blockIdx.x;             // b*128 + kt
    const int s0  = (bt & 127) * TK;
    const int b   = bt >> 7;
    const float* xsrc = x + ((size_t)(b * S_ + s0)) * D_;
    const int r_ = tid >> 4, c_ = tid & 15;
    #pragma unroll
    for (int it = 0; it < 12; ++it) {
        const int col4 = c_ + it * 16;
        *(float4*)&xs[r_][col4 * 4] = *(const float4*)&xsrc[(size_t)r_ * D_ + col4 * 4];
    }
    __syncthreads();

    unsigned short* dst = xTg + (size_t)bt * XT_TILE;
    #pragma unroll
    for (int it = 0; it < 6; ++it) {
        const int cch = it * 512 + tid;
        const int col = cch & 31;
        const int kh  = (cch >> 5) & 1;
        const int db  = (cch >> 6) % 24;
        const int kw  = (cch >> 6) / 24;
        const int d   = db * 32 + col;
        const int sr  = kw * 16 + kh * 8;
        short8 v;
        #pragma unroll
        for (int e = 0; e < 8; ++e) v[e] = (short)f2bf(xs[sr + e][d]);
        *(short8*)&dst[cch * 8] = v;
    }
}

// ---------------- kernel 4: flash attention, D-split, 2 blocks/CU ----------------
__global__ __launch_bounds__(NTHR, 3) void attn_k(const unsigned short* __restrict__ xTg,
                                                  const unsigned short* __restrict__ qg,
                                                  const unsigned short* __restrict__ kg,
                                                  const float* __restrict__ maskf,
                                                  float* __restrict__ out) {
    __shared__ __align__(16) unsigned short xT_l[2][XT_HALF];   // 2 x 24KB
    __shared__ __align__(16) unsigned short k_l[2][K_TILE];     // 2 x 4KB
    __shared__ __align__(16) unsigned short q_l[Q_TILE];        // 8KB
    __shared__ __align__(16) unsigned short p_l[TQ * TK];       // 4KB
    __shared__ __align__(16) float mk_l[2][TK];
    __shared__ __align__(16) float scale_l[TQ];
    __shared__ __align__(16) float inv_l[TQ];
    __shared__ int flag_l[4];

    const int tid = threadIdx.x;
    const int w = tid >> 6;
    const int l = tid & 63;
    const int lg = l >> 4;
    // XCD-aware remap: raw%8 selects (b,h) -> all 64 blocks of one xT-half
    // stream land on one XCD; 3MB stream fits its 4MB L2.
    const int raw = blockIdx.x;
    const int bh  = raw & 7;
    const int qt  = raw >> 3;          // 0..63
    const int b   = bh >> 1;
    const int h   = bh & 1;            // d-half
    const int qbase = qt * TQ;
    const int bS = b * S_;
    const unsigned short* xT_t = xTg + (size_t)b * NT * XT_TILE;
    const unsigned short* kg_t = kg + (size_t)b * NT * K_TILE;
    const float* mk_g = maskf + bS;

#define STAGE_ALL(buf, ktile)                                                          \
    {                                                                                  \
        const unsigned short* xs_ = xT_t + (size_t)(ktile) * XT_TILE + h * (768 * 8);  \
        _Pragma("unroll")                                                              \
        for (int i_ = 0; i_ < 4; ++i_) {                                               \
            const int c_ = i_ * NTHR + tid;                                            \
            const int src_ = (i_ < 2) ? c_ : c_ + 768;                                 \
            GLOAD16(xs_ + src_ * 8, &xT_l[buf][c_ * 8]);                               \
        }                                                                              \
        if (tid < 256)                                                                 \
            GLOAD16(kg_t + (size_t)(ktile) * K_TILE + tid * 8, &k_l[buf][tid * 8]);    \
        if (tid < 8) GLOAD16(mk_g + (ktile) * TK + tid * 4, &mk_l[buf][tid * 4]);      \
    }

    // ---- prologue staging ----
    {
        const unsigned short* qsrc = qg + (size_t)(b * 64 + qt) * Q_TILE;
        GLOAD16(qsrc + tid * 8, &q_l[tid * 8]);
        if (tid < 128) GLOAD16(qsrc + (NTHR + tid) * 8, &q_l[(NTHR + tid) * 8]);
    }
    STAGE_ALL(0, 0);
    asm volatile("s_waitcnt vmcnt(0)" ::: "memory");
    __syncthreads();

    short8 qf[2];
    float m_run = -1e30f, l_run = 0.f;
    if (w < 4) {
        #pragma unroll
        for (int hh = 0; hh < 2; ++hh)
            qf[hh] = *(const short8*)&q_l[(((w * 2 + hh) * 4 + lg) * 16 + (l & 15)) * 8];
    }

    f32x16 acc[2][2];
    {
        f32x16 z = {0.f};
        #pragma unroll
        for (int i = 0; i < 2; ++i)
            #pragma unroll
            for (int j = 0; j < 2; ++j) acc[i][j] = z;
    }

    int cur = 0;
    for (int kt = 0; kt < NT; ++kt) {
        // ---------- phase A: stage next tile (all waves) + QK^T/softmax (waves 0-3) ----------
        if (kt + 1 < NT) STAGE_ALL(cur ^ 1, kt + 1);
        if (w < 4) {
            const int qloc = (w << 4) + (l & 15);
            f32x4 c0 = {0.f, 0.f, 0.f, 0.f};
            f32x4 c1 = {0.f, 0.f, 0.f, 0.f};
            #pragma unroll
            for (int hh = 0; hh < 2; ++hh) {
                const short8 a0 = *(const short8*)&k_l[cur][(((hh * 2 + 0) * 4 + lg) * 16 + (l & 15)) * 8];
                const short8 a1 = *(const short8*)&k_l[cur][(((hh * 2 + 1) * 4 + lg) * 16 + (l & 15)) * 8];
                c0 = __builtin_amdgcn_mfma_f32_16x16x32_bf16(a0, qf[hh], c0, 0, 0, 0);
                c1 = __builtin_amdgcn_mfma_f32_16x16x32_bf16(a1, qf[hh], c1, 0, 0, 0);
            }
            float s[8], mv[8];
            const float4 mk0 = *(const float4*)&mk_l[cur][lg << 2];
            const float4 mk1 = *(const float4*)&mk_l[cur][16 + (lg << 2)];
            mv[0] = mk0.x; mv[1] = mk0.y; mv[2] = mk0.z; mv[3] = mk0.w;
            mv[4] = mk1.x; mv[5] = mk1.y; mv[6] = mk1.z; mv[7] = mk1.w;
            #pragma unroll
            for (int r = 0; r < 4; ++r) {
                s[r]     = (mv[r]     > 0.f) ? c0[r] * 0.125f : -1e30f;
                s[4 + r] = (mv[4 + r] > 0.f) ? c1[r] * 0.125f : -1e30f;
            }
            float mx = s[0];
            #pragma unroll
            for (int r = 1; r < 8; ++r) mx = fmaxf(mx, s[r]);
            mx = fmaxf(mx, __shfl_xor(mx, 16));
            mx = fmaxf(mx, __shfl_xor(mx, 32));
            const bool upd = (mx > m_run + 8.f);   // defer-max (T13)
            float sc = 1.f;
            if (upd) { sc = __expf(m_run - mx); m_run = mx; }
            float p[8], ps = 0.f;
            #pragma unroll
            for (int r = 0; r < 8; ++r) { p[r] = mv[r] * __expf(s[r] - m_run); ps += p[r]; }
            ps += __shfl_xor(ps, 16);
            ps += __shfl_xor(ps, 32);
            l_run = l_run * sc + ps;
            if (lg == 0) scale_l[qloc] = sc;
            const int fl = __any(upd);
            if (l == 0) flag_l[w] = fl;
            // pack p -> bf16 A-fragments
            const int qh = qloc >> 5, qr = qloc & 31;
            const int kh = lg >> 1, eb = (lg & 1) << 2;
            #pragma unroll
            for (int t = 0; t < 2; ++t) {
                unsigned long long pk =
                      (unsigned long long)f2bf(p[t * 4 + 0])
                    | ((unsigned long long)f2bf(p[t * 4 + 1]) << 16)
                    | ((unsigned long long)f2bf(p[t * 4 + 2]) << 32)
                    | ((unsigned long long)f2bf(p[t * 4 + 3]) << 48);
                const int chunk = ((t * 2 + qh) * 2 + kh) * 32 + qr;
                *(unsigned long long*)&p_l[chunk * 8 + eb] = pk;
            }
            asm volatile("s_waitcnt lgkmcnt(0)" ::: "memory");
        }
        BARRIER();   // B1: p/scale/flag published; staged loads stay in flight

        // ---------- phase B: PV (all 6 waves; wave w owns local d-blocks 2w, 2w+1) ----------
        const int anyf = flag_l[0] + flag_l[1] + flag_l[2] + flag_l[3];
        if (anyf) {
            #pragma unroll
            for (int i = 0; i < 2; ++i) {
                #pragma unroll
                for (int g = 0; g < 4; ++g) {
                    const float4 sv = *(const float4*)&scale_l[(i << 5) + ((l >> 5) << 2) + (g << 3)];
                    #pragma unroll
                    for (int j = 0; j < 2; ++j) {
                        acc[i][j][(g << 2) + 0] *= sv.x;
                        acc[i][j][(g << 2) + 1] *= sv.y;
                        acc[i][j][(g << 2) + 2] *= sv.z;
                        acc[i][j][(g << 2) + 3] *= sv.w;
                    }
                }
            }
        }
        {
            const int khp = l >> 5;
            #pragma unroll
            for (int t = 0; t < 2; ++t) {
                const short8 a0 = *(const short8*)&p_l[(((t * 2 + 0) * 2 + khp) * 32 + (l & 31)) * 8];
                const short8 a1 = *(const short8*)&p_l[(((t * 2 + 1) * 2 + khp) * 32 + (l & 31)) * 8];
                #pragma unroll
                for (int j = 0; j < 2; ++j) {
                    const int dbL = w * 2 + j;
                    const short8 bv = *(const short8*)&xT_l[cur][(((t * 12 + dbL) * 2 + khp) * 32 + (l & 31)) * 8];
                    acc[0][j] = __builtin_amdgcn_mfma_f32_32x32x16_bf16(a0, bv, acc[0][j], 0, 0, 0);
                    acc[1][j] = __builtin_amdgcn_mfma_f32_32x32x16_bf16(a1, bv, acc[1][j], 0, 0, 0);
                }
            }
        }
        __syncthreads();   // B2: drains staged vmcnt; protects p/k/xT reuse
        cur ^= 1;
    }

    // ---------- epilogue: 1/l, query mask, store ----------
    if (w < 4 && lg == 0) {
        const int qloc = (w << 4) + (l & 15);
        const float mq = maskf[(size_t)bS + qbase + qloc];
        inv_l[qloc] = (mq > 0.f && l_run > 0.f) ? (1.f / l_run) : 0.f;
    }
    __syncthreads();
    #pragma unroll
    for (int i = 0; i < 2; ++i) {
        #pragma unroll
        for (int g = 0; g < 4; ++g) {
            const float4 iv = *(const float4*)&inv_l[(i << 5) + ((l >> 5) << 2) + (g << 3)];
            #pragma unroll
            for (int j = 0; j < 2; ++j) {
                const int dcol = h * DH + (w * 2 + j) * 32 + (l & 31);
                #pragma unroll
                for (int e = 0; e < 4; ++e) {
                    const int row = (i << 5) + ((l >> 5) << 2) + (g << 3) + e;
                    const float ivv = (e == 0) ? iv.x : (e == 1) ? iv.y : (e == 2) ? iv.z : iv.w;
                    out[(size_t)(bS + qbase + row) * D_ + dcol] = acc[i][j][(g << 2) + e] * ivv;
                }
            }
        }
    }
#undef STAGE_ALL
}

extern "C" void kernel_launch(void* const* d_in, const int* in_sizes, int n_in,
                              void* d_out, int out_size, void* d_ws, size_t ws_size,
                              hipStream_t stream) {
    const float*         x    = (const float*)d_in[0];
    const unsigned char* mraw = (const unsigned char*)d_in[1];
    const float*         Wq   = (const float*)d_in[2];
    const float*         Wk   = (const float*)d_in[3];
    float*               outp = (float*)d_out;

    float* maskf = (float*)d_ws;
    unsigned short* qg  = (unsigned short*)(maskf + (size_t)B_ * S_);
    unsigned short* kg  = qg + (size_t)B_ * S_ * U_;
    unsigned short* xTg = kg + (size_t)B_ * S_ * U_;

    decode_mask_k<<<(B_ * S_) / 256, 256, 0, stream>>>(mraw, maskf);
    proj_qk_k<<<(B_ * S_) / 16, 256, 0, stream>>>(x, Wq, Wk, qg, kg);
    xpose_k<<<B_ * (S_ / TK), 512, 0, stream>>>(x, xTg);
    attn_k<<<B_ * (S_ / TQ) * 2, NTHR, 0, stream>>>(xTg, qg, kg, maskf, outp);
}

// Round 7
// 375.724 us; speedup vs baseline: 1.0552x; 1.0552x over previous
//
#include <hip/hip_runtime.h>
#include <math.h>

#define B_ 4
#define S_ 4096
#define D_ 768
#define U_ 64
#define TQ 64
#define TK 32
#define NT (S_ / TK)
#define XT_TILE (TK * D_)   // 24576 elems (48KB) per key-tile, fragment-ordered
#define K_TILE  (TK * U_)   // 2048 elems (4KB)
#define Q_TILE  (TQ * U_)   // 4096 elems (8KB)

typedef __attribute__((ext_vector_type(8))) short short8;
typedef __attribute__((ext_vector_type(4))) float f32x4;
typedef __attribute__((ext_vector_type(16))) float f32x16;

__device__ __forceinline__ unsigned short f2bf(float f) {
    unsigned int x = __float_as_uint(f);
    unsigned int r = (x + 0x7fffu + ((x >> 16) & 1u)) >> 16;
    return (unsigned short)r;
}

#define GLOAD16(gsrc, ldst)                                                             \
    __builtin_amdgcn_global_load_lds(                                                   \
        (const __attribute__((address_space(1))) unsigned int*)(const void*)(gsrc),     \
        (__attribute__((address_space(3))) unsigned int*)(void*)(ldst), 16, 0, 0)

// ---------------- kernel 1: decode mask (auto-detect bool8 vs int32) ----------------
__global__ __launch_bounds__(256) void decode_mask_k(const unsigned char* __restrict__ mraw,
                                                     float* __restrict__ maskf) {
    int base = threadIdx.x * 4;
    int bad = (mraw[base + 1] | mraw[base + 2] | mraw[base + 3]) != 0;
    int isbyte = __syncthreads_or(bad);
    int i = blockIdx.x * 256 + threadIdx.x;
    if (i < B_ * S_) {
        int v = isbyte ? (int)mraw[i] : ((const int*)mraw)[i];
        maskf[i] = (v != 0) ? 1.0f : 0.0f;
    }
}

// ---------------- kernel 2: q/k projection -> bf16, MFMA-fragment-ordered ----------------
__global__ __launch_bounds__(256) void proj_qk_k(const float* __restrict__ x,
                                                 const float* __restrict__ Wq,
                                                 const float* __restrict__ Wk,
                                                 unsigned short* __restrict__ qg,
                                                 unsigned short* __restrict__ kg) {
    __shared__ float xs[16][D_];
    const int rbase = blockIdx.x * 16;
    const float4* xsrc = (const float4*)(x + (size_t)rbase * D_);
    float4* xdst = (float4*)&xs[0][0];
    for (int i = threadIdx.x; i < 16 * D_ / 4; i += 256) xdst[i] = xsrc[i];
    __syncthreads();

    const int c  = threadIdx.x & 127;
    const int rg = threadIdx.x >> 7;
    const float* __restrict__ W = (c < 64) ? Wq : Wk;
    const int u = c & 63;

    float acc[8] = {0.f, 0.f, 0.f, 0.f, 0.f, 0.f, 0.f, 0.f};
    #pragma unroll 4
    for (int d = 0; d < D_; ++d) {
        const float wv = W[d * U_ + u];
        #pragma unroll
        for (int r = 0; r < 8; ++r) acc[r] = fmaf(xs[rg * 8 + r][d], wv, acc[r]);
    }

    const int h  = u >> 5;
    const int lg = (u >> 3) & 3;
    const int e  = u & 7;
    const int row0 = rbase + rg * 8;
    if (c < 64) {
        unsigned short* dstq = qg + (size_t)(row0 >> 6) * Q_TILE
            + ((((((row0 >> 4) & 3) * 2 + h) * 4 + lg) * 16) + (row0 & 15)) * 8 + e;
        #pragma unroll
        for (int r = 0; r < 8; ++r) dstq[r * 8] = f2bf(acc[r]);
    } else {
        unsigned short* dstk = kg + (size_t)(row0 >> 5) * K_TILE
            + (((h * 2 + ((row0 >> 4) & 1)) * 4 + lg) * 16 + (row0 & 15)) * 8 + e;
        #pragma unroll
        for (int r = 0; r < 8; ++r) dstk[r * 8] = f2bf(acc[r]);
    }
}

// ---------------- kernel 3: x -> xT B-fragments, per (b, key-tile) ----------------
__global__ __launch_bounds__(512) void xpose_k(const float* __restrict__ x,
                                               unsigned short* __restrict__ xTg) {
    __shared__ float xs[TK][D_ + 4];
    const int tid = threadIdx.x;
    const int bt  = blockIdx.x;             // b*128 + kt
    const int s0  = (bt & 127) * TK;
    const int b   = bt >> 7;
    const float* xsrc = x + ((size_t)(b * S_ + s0)) * D_;
    const int r_ = tid >> 4, c_ = tid & 15;
    #pragma unroll
    for (int it = 0; it < 12; ++it) {
        const int col4 = c_ + it * 16;
        *(float4*)&xs[r_][col4 * 4] = *(const float4*)&xsrc[(size_t)r_ * D_ + col4 * 4];
    }
    __syncthreads();

    unsigned short* dst = xTg + (size_t)bt * XT_TILE;
    #pragma unroll
    for (int it = 0; it < 6; ++it) {
        const int cch = it * 512 + tid;
        const int col = cch & 31;
        const int kh  = (cch >> 5) & 1;
        const int db  = (cch >> 6) % 24;
        const int kw  = (cch >> 6) / 24;
        const int d   = db * 32 + col;
        const int sr  = kw * 16 + kh * 8;
        short8 v;
        #pragma unroll
        for (int e = 0; e < 8; ++e) v[e] = (short)f2bf(xs[sr + e][d]);
        *(short8*)&dst[cch * 8] = v;
    }
}

// ------- kernel 4: flash attention, producer/consumer waves, __syncthreads-only -------
// waves 0-3: QK^T + softmax for tile t+1; waves 4-7: PV for tile t (192 d-cols each).
// One __syncthreads per iteration (full vm+lgkm drain in every wave, as in proven R3).
__global__ __launch_bounds__(512, 2) void attn_k(const unsigned short* __restrict__ xTg,
                                                 const unsigned short* __restrict__ qg,
                                                 const unsigned short* __restrict__ kg,
                                                 const float* __restrict__ maskf,
                                                 float* __restrict__ out) {
    __shared__ __align__(16) unsigned short xT_l[2][XT_TILE];   // 96KB
    __shared__ __align__(16) unsigned short k_l[4][K_TILE];     // 16KB
    __shared__ __align__(16) unsigned short q_l[Q_TILE];        // 8KB
    __shared__ __align__(16) unsigned short p_l[2][TQ * TK];    // 8KB
    __shared__ __align__(16) float scale_l[2][TQ];
    __shared__ __align__(16) float inv_l[TQ];
    __shared__ int flag_l[2][4];

    const int tid = threadIdx.x;
    const int w = tid >> 6;
    const int l = tid & 63;
    const int lg = l >> 4;
    // XCD remap: raw&7 -> (b, qt-parity); each XCD's blocks share one batch's xT stream.
    const int raw = blockIdx.x;
    const int bh = raw & 7;
    const int b = bh >> 1;
    const int qt = ((raw >> 3) << 1) + (bh & 1);
    const int qbase = qt * TQ;
    const int bS = b * S_;
    const unsigned short* xT_t = xTg + (size_t)b * NT * XT_TILE;
    const unsigned short* kg_t = kg + (size_t)b * NT * K_TILE;
    const float* mk_g = maskf + bS;
    const bool prod = (w < 4);
    const int cw = w & 3;   // consumer index (waves 4-7)

// all 8 waves: 6 GLOAD16 each (3072 chunks / 8 waves)
#define ISSUE_XT(buf, ktile)                                                  \
    {                                                                         \
        const unsigned short* xs_ = xT_t + (size_t)(ktile) * XT_TILE;         \
        _Pragma("unroll")                                                     \
        for (int i_ = 0; i_ < 6; ++i_) {                                      \
            const int ch_ = w * 384 + i_ * 64 + l;                            \
            GLOAD16(xs_ + ch_ * 8, &xT_l[buf][ch_ * 8]);                      \
        }                                                                     \
    }

// producers: k chunk (quarter per wave)
#define ISSUE_K(slot, ktile)                                                  \
    {                                                                         \
        GLOAD16(kg_t + (size_t)(ktile) * K_TILE + (w * 64 + l) * 8,           \
                &k_l[slot][(w * 64 + l) * 8]);                                \
    }

    // ---- prologue staging ----
    GLOAD16(qg + (size_t)(b * 64 + qt) * Q_TILE + tid * 8, &q_l[tid * 8]);
    ISSUE_XT(0, 0);
    if (prod) { ISSUE_K(0, 0); ISSUE_K(1, 1); }
    __syncthreads();   // drains vm+lgkm in all waves

    short8 qf[2];
    float m_run = -1e30f, l_run = 0.f;
    if (prod) {
        #pragma unroll
        for (int hh = 0; hh < 2; ++hh)
            qf[hh] = *(const short8*)&q_l[(((w * 2 + hh) * 4 + lg) * 16 + (l & 15)) * 8];
    }

    f32x16 acc[2][6];
    {
        f32x16 z = {0.f};
        #pragma unroll
        for (int i = 0; i < 2; ++i)
            #pragma unroll
            for (int j = 0; j < 6; ++j) acc[i][j] = z;
    }

    // producer softmax for `tile`, writing p/scale/flag buffer `pb`; mask read from global
    auto softmax_step = [&](int tile, int pb) {
        const int slot = tile & 3;
        const int qloc = (w << 4) + (l & 15);
        f32x4 c0 = {0.f, 0.f, 0.f, 0.f};
        f32x4 c1 = {0.f, 0.f, 0.f, 0.f};
        #pragma unroll
        for (int hh = 0; hh < 2; ++hh) {
            const short8 a0 = *(const short8*)&k_l[slot][(((hh * 2 + 0) * 4 + lg) * 16 + (l & 15)) * 8];
            const short8 a1 = *(const short8*)&k_l[slot][(((hh * 2 + 1) * 4 + lg) * 16 + (l & 15)) * 8];
            c0 = __builtin_amdgcn_mfma_f32_16x16x32_bf16(a0, qf[hh], c0, 0, 0, 0);
            c1 = __builtin_amdgcn_mfma_f32_16x16x32_bf16(a1, qf[hh], c1, 0, 0, 0);
        }
        float s[8], mv[8];
        const float4 mk0 = *(const float4*)(mk_g + tile * TK + (lg << 2));
        const float4 mk1 = *(const float4*)(mk_g + tile * TK + 16 + (lg << 2));
        mv[0] = mk0.x; mv[1] = mk0.y; mv[2] = mk0.z; mv[3] = mk0.w;
        mv[4] = mk1.x; mv[5] = mk1.y; mv[6] = mk1.z; mv[7] = mk1.w;
        #pragma unroll
        for (int r = 0; r < 4; ++r) {
            s[r]     = (mv[r]     > 0.f) ? c0[r] * 0.125f : -1e30f;
            s[4 + r] = (mv[4 + r] > 0.f) ? c1[r] * 0.125f : -1e30f;
        }
        float mx = s[0];
        #pragma unroll
        for (int r = 1; r < 8; ++r) mx = fmaxf(mx, s[r]);
        mx = fmaxf(mx, __shfl_xor(mx, 16));
        mx = fmaxf(mx, __shfl_xor(mx, 32));
        const bool upd = (mx > m_run + 8.f);   // defer-max (T13)
        float sc = 1.f;
        if (upd) { sc = __expf(m_run - mx); m_run = mx; }
        float p[8], ps = 0.f;
        #pragma unroll
        for (int r = 0; r < 8; ++r) { p[r] = mv[r] * __expf(s[r] - m_run); ps += p[r]; }
        ps += __shfl_xor(ps, 16);
        ps += __shfl_xor(ps, 32);
        l_run = l_run * sc + ps;
        if (lg == 0) scale_l[pb][qloc] = sc;
        const int fl = __any(upd);
        if (l == 0) flag_l[pb][w] = fl;
        const int qh = qloc >> 5, qr = qloc & 31;
        const int kh = lg >> 1, eb = (lg & 1) << 2;
        #pragma unroll
        for (int t2 = 0; t2 < 2; ++t2) {
            unsigned long long pk =
                  (unsigned long long)f2bf(p[t2 * 4 + 0])
                | ((unsigned long long)f2bf(p[t2 * 4 + 1]) << 16)
                | ((unsigned long long)f2bf(p[t2 * 4 + 2]) << 32)
                | ((unsigned long long)f2bf(p[t2 * 4 + 3]) << 48);
            const int chunk = ((t2 * 2 + qh) * 2 + kh) * 32 + qr;
            *(unsigned long long*)&p_l[pb][chunk * 8 + eb] = pk;
        }
    };

    // pre-loop: softmax(0) so PV(0) has p ready
    if (prod) softmax_step(0, 0);
    __syncthreads();

    for (int t = 0; t < NT; ++t) {
        const int pb = t & 1;
        if (t + 1 < NT) ISSUE_XT((t + 1) & 1, t + 1);   // all waves issue early
        if (prod) {
            if (t + 2 < NT) ISSUE_K((t + 2) & 3, t + 2);
            if (t + 1 < NT) softmax_step(t + 1, (t + 1) & 1);
        } else {
            const int anyf = flag_l[pb][0] + flag_l[pb][1] + flag_l[pb][2] + flag_l[pb][3];
            if (anyf) {
                #pragma unroll
                for (int i = 0; i < 2; ++i) {
                    #pragma unroll
                    for (int g = 0; g < 4; ++g) {
                        const float4 sv = *(const float4*)&scale_l[pb][(i << 5) + ((l >> 5) << 2) + (g << 3)];
                        #pragma unroll
                        for (int j = 0; j < 6; ++j) {
                            acc[i][j][(g << 2) + 0] *= sv.x;
                            acc[i][j][(g << 2) + 1] *= sv.y;
                            acc[i][j][(g << 2) + 2] *= sv.z;
                            acc[i][j][(g << 2) + 3] *= sv.w;
                        }
                    }
                }
            }
            const int khp = l >> 5;
            #pragma unroll
            for (int t2 = 0; t2 < 2; ++t2) {
                const short8 a0 = *(const short8*)&p_l[pb][(((t2 * 2 + 0) * 2 + khp) * 32 + (l & 31)) * 8];
                const short8 a1 = *(const short8*)&p_l[pb][(((t2 * 2 + 1) * 2 + khp) * 32 + (l & 31)) * 8];
                #pragma unroll
                for (int j = 0; j < 6; ++j) {
                    const int db = cw * 6 + j;
                    const short8 bv = *(const short8*)&xT_l[pb][(((t2 * 24 + db) * 2 + khp) * 32 + (l & 31)) * 8];
                    acc[0][j] = __builtin_amdgcn_mfma_f32_32x32x16_bf16(a0, bv, acc[0][j], 0, 0, 0);
                    acc[1][j] = __builtin_amdgcn_mfma_f32_32x32x16_bf16(a1, bv, acc[1][j], 0, 0, 0);
                }
            }
        }
        __syncthreads();   // full drain (vm+lgkm) in every wave, then barrier
    }

    // ---------- epilogue ----------
    if (prod && lg == 0) {
        const int qloc = (w << 4) + (l & 15);
        const float mq = maskf[(size_t)bS + qbase + qloc];
        inv_l[qloc] = (mq > 0.f && l_run > 0.f) ? (1.f / l_run) : 0.f;
    }
    __syncthreads();
    if (!prod) {
        #pragma unroll
        for (int i = 0; i < 2; ++i) {
            #pragma unroll
            for (int g = 0; g < 4; ++g) {
                const float4 iv = *(const float4*)&inv_l[(i << 5) + ((l >> 5) << 2) + (g << 3)];
                #pragma unroll
                for (int j = 0; j < 6; ++j) {
                    const int dcol = (cw * 6 + j) * 32 + (l & 31);
                    #pragma unroll
                    for (int e = 0; e < 4; ++e) {
                        const int row = (i << 5) + ((l >> 5) << 2) + (g << 3) + e;
                        const float ivv = (e == 0) ? iv.x : (e == 1) ? iv.y : (e == 2) ? iv.z : iv.w;
                        out[(size_t)(bS + qbase + row) * D_ + dcol] = acc[i][j][(g << 2) + e] * ivv;
                    }
                }
            }
        }
    }
#undef ISSUE_XT
#undef ISSUE_K
}

extern "C" void kernel_launch(void* const* d_in, const int* in_sizes, int n_in,
                              void* d_out, int out_size, void* d_ws, size_t ws_size,
                              hipStream_t stream) {
    const float*         x    = (const float*)d_in[0];
    const unsigned char* mraw = (const unsigned char*)d_in[1];
    const float*         Wq   = (const float*)d_in[2];
    const float*         Wk   = (const float*)d_in[3];
    float*               outp = (float*)d_out;

    float* maskf = (float*)d_ws;
    unsigned short* qg  = (unsigned short*)(maskf + (size_t)B_ * S_);
    unsigned short* kg  = qg + (size_t)B_ * S_ * U_;
    unsigned short* xTg = kg + (size_t)B_ * S_ * U_;

    decode_mask_k<<<(B_ * S_) / 256, 256, 0, stream>>>(mraw, maskf);
    proj_qk_k<<<(B_ * S_) / 16, 256, 0, stream>>>(x, Wq, Wk, qg, kg);
    xpose_k<<<B_ * (S_ / TK), 512, 0, stream>>>(x, xTg);
    attn_k<<<B_ * (S_ / TQ), 512, 0, stream>>>(xTg, qg, kg, maskf, outp);
}

// Round 8
// 295.558 us; speedup vs baseline: 1.3415x; 1.2712x over previous
//
#include <hip/hip_runtime.h>
#include <math.h>

#define B_ 4
#define S_ 4096
#define D_ 768
#define U_ 64
#define TK 32
#define NT (S_ / TK)
#define XT_TILE (TK * D_)   // 24576 elems (48KB) per key-tile, B-fragment-ordered
#define QK_TILE 2048        // per 32-row q/k tile: 4 frags x 64 lanes x 8 elems

typedef __attribute__((ext_vector_type(8))) short short8;
typedef __attribute__((ext_vector_type(16))) float f32x16;

__device__ __forceinline__ unsigned short f2bf(float f) {
    unsigned int x = __float_as_uint(f);
    unsigned int r = (x + 0x7fffu + ((x >> 16) & 1u)) >> 16;
    return (unsigned short)r;
}

// ---------------- kernel 1: decode mask -> q-mask float + key bias float ----------------
__global__ __launch_bounds__(256) void decode_mask_k(const unsigned char* __restrict__ mraw,
                                                     float* __restrict__ maskf,
                                                     float* __restrict__ biasf) {
    int base = threadIdx.x * 4;
    int bad = (mraw[base + 1] | mraw[base + 2] | mraw[base + 3]) != 0;
    int isbyte = __syncthreads_or(bad);
    int i = blockIdx.x * 256 + threadIdx.x;
    if (i < B_ * S_) {
        int v = isbyte ? (int)mraw[i] : ((const int*)mraw)[i];
        maskf[i] = (v != 0) ? 1.0f : 0.0f;
        biasf[i] = (v != 0) ? 0.0f : -1e30f;
    }
}

// ------- kernel 2: q/k projection -> bf16 32x32x16 A/B fragments per 32-row tile -------
// elem [row][u] -> tile=row>>5, frag m=u>>4, lane=(row&31)+32*((u>>3)&1), byte e=u&7
__global__ __launch_bounds__(256) void proj_qk_k(const float* __restrict__ x,
                                                 const float* __restrict__ Wq,
                                                 const float* __restrict__ Wk,
                                                 unsigned short* __restrict__ qg,
                                                 unsigned short* __restrict__ kg) {
    __shared__ float xs[16][D_];
    const int rbase = blockIdx.x * 16;
    const float4* xsrc = (const float4*)(x + (size_t)rbase * D_);
    float4* xdst = (float4*)&xs[0][0];
    for (int i = threadIdx.x; i < 16 * D_ / 4; i += 256) xdst[i] = xsrc[i];
    __syncthreads();

    const int c  = threadIdx.x & 127;
    const int rg = threadIdx.x >> 7;
    const float* __restrict__ W = (c < 64) ? Wq : Wk;
    const int u = c & 63;

    float acc[8] = {0.f, 0.f, 0.f, 0.f, 0.f, 0.f, 0.f, 0.f};
    #pragma unroll 4
    for (int d = 0; d < D_; ++d) {
        const float wv = W[d * U_ + u];
        #pragma unroll
        for (int r = 0; r < 8; ++r) acc[r] = fmaf(xs[rg * 8 + r][d], wv, acc[r]);
    }

    const int m  = u >> 4;
    const int b3 = (u >> 3) & 1;
    const int e  = u & 7;
    const int row0 = rbase + rg * 8;
    unsigned short* dst = ((c < 64) ? qg : kg)
        + (size_t)(row0 >> 5) * QK_TILE
        + ((m * 64) + (row0 & 31) + 32 * b3) * 8 + e;
    #pragma unroll
    for (int r = 0; r < 8; ++r) dst[r * 8] = f2bf(acc[r]);
}

// ---------------- kernel 3: x -> xT B-fragments, per (b, key-tile) ----------------
__global__ __launch_bounds__(512) void xpose_k(const float* __restrict__ x,
                                               unsigned short* __restrict__ xTg) {
    __shared__ float xs[TK][D_ + 4];
    const int tid = threadIdx.x;
    const int bt  = blockIdx.x;             // b*128 + kt
    const int s0  = (bt & 127) * TK;
    const int b   = bt >> 7;
    const float* xsrc = x + ((size_t)(b * S_ + s0)) * D_;
    const int r_ = tid >> 4, c_ = tid & 15;
    #pragma unroll
    for (int it = 0; it < 12; ++it) {
        const int col4 = c_ + it * 16;
        *(float4*)&xs[r_][col4 * 4] = *(const float4*)&xsrc[(size_t)r_ * D_ + col4 * 4];
    }
    __syncthreads();

    unsigned short* dst = xTg + (size_t)bt * XT_TILE;
    #pragma unroll
    for (int it = 0; it < 6; ++it) {
        const int cch = it * 512 + tid;
        const int col = cch & 31;
        const int kh  = (cch >> 5) & 1;
        const int db  = (cch >> 6) % 24;
        const int kw  = (cch >> 6) / 24;
        const int d   = db * 32 + col;
        const int sr  = kw * 16 + kh * 8;
        short8 v;
        #pragma unroll
        for (int e = 0; e < 8; ++e) v[e] = (short)f2bf(xs[sr + e][d]);
        *(short8*)&dst[cch * 8] = v;
    }
}

// ------- kernel 4: flash attention, wave-autonomous (no barriers in main loop) -------
// Wave = (qtile: 32 q-rows, dg: 192 d-cols). QK duplicated per dg; softmax lane-local;
// p via 2KB wave-private LDS; xT/K/Q/bias loaded global->reg (L2-hot scratch).
__global__ __launch_bounds__(512, 2) void attn_k(const unsigned short* __restrict__ xTg,
                                                 const unsigned short* __restrict__ qg,
                                                 const unsigned short* __restrict__ kg,
                                                 const float* __restrict__ maskf,
                                                 const float* __restrict__ biasf,
                                                 float* __restrict__ out) {
    __shared__ float sc_l[8][32];                            // per-wave scale/inv broadcast
    __shared__ __align__(16) unsigned short p_l[8][1024];    // per-wave p A-frags (2KB)

    const int tid = threadIdx.x;
    const int w = tid >> 6;
    const int l = tid & 63;
    const int hi = l >> 5;
    const int q5 = l & 31;
    // XCD remap: raw&7 -> (b, parity). 32 blocks/XCD share one batch; parity staggers
    // the tile start by 64 so each XCD's hot xT window (~3MB) fits its 4MB L2.
    const int raw = blockIdx.x;
    const int bh = raw & 7;
    const int b = bh >> 1;
    const int par = bh & 1;
    const int qpair = (raw >> 3) * 2 + par;      // 0..63
    const int qtile = qpair * 2 + (w >> 2);      // 0..127
    const int dg = w & 3;
    const int bS = b * S_;
    const int q0 = qtile * 32;
    const int t0 = par * 64;

    const unsigned short* xT_b = xTg + (size_t)b * NT * XT_TILE;
    const unsigned short* kg_b = kg + (size_t)(b * NT) * QK_TILE;
    const float* bias_b = biasf + bS;
    unsigned short* pw = &p_l[w][0];

    // Q B-fragments (held whole kernel)
    short8 qf[4];
    {
        const unsigned short* qp = qg + (size_t)(b * NT + qtile) * QK_TILE;
        #pragma unroll
        for (int m = 0; m < 4; ++m) qf[m] = *(const short8*)(qp + (m * 64 + l) * 8);
    }

    f32x16 acc[6];
    {
        f32x16 z = {0.f};
        #pragma unroll
        for (int j = 0; j < 6; ++j) acc[j] = z;
    }
    float m_run = -1e30f, l_run = 0.f;

    short8 kfA[4], kfB[4];
    {
        const unsigned short* kp = kg_b + (size_t)t0 * QK_TILE;
        #pragma unroll
        for (int m = 0; m < 4; ++m) kfA[m] = *(const short8*)(kp + (m * 64 + l) * 8);
    }

    auto step = [&](int it, short8 (&kcur)[4], short8 (&knxt)[4]) {
        const int tt = (t0 + it) & (NT - 1);
        const int tn = (t0 + it + 1) & (NT - 1);
        // bias loads (needed first)
        const float* bt = bias_b + tt * TK;
        float4 b4[4];
        #pragma unroll
        for (int g = 0; g < 4; ++g) b4[g] = *(const float4*)(bt + g * 8 + hi * 4);
        // xT B-frags for this wave's 6 d-blocks x 2 k-halves (used at end of step)
        const unsigned short* xt = xT_b + (size_t)tt * XT_TILE;
        short8 xv[12];
        #pragma unroll
        for (int kw = 0; kw < 2; ++kw)
            #pragma unroll
            for (int j = 0; j < 6; ++j)
                xv[kw * 6 + j] = *(const short8*)(xt + ((kw * 24 + dg * 6 + j) * 64 + l) * 8);
        // K prefetch for next tile
        const unsigned short* kp = kg_b + (size_t)tn * QK_TILE;
        #pragma unroll
        for (int m = 0; m < 4; ++m) knxt[m] = *(const short8*)(kp + (m * 64 + l) * 8);
        // QK^T: C[key][q], lane: q=l&31, key(r)=(r&3)+8*(r>>2)+4*hi
        f32x16 c = {0.f};
        #pragma unroll
        for (int m = 0; m < 4; ++m)
            c = __builtin_amdgcn_mfma_f32_32x32x16_bf16(kcur[m], qf[m], c, 0, 0, 0);
        // scores: mask as additive bias (-1e30), single fma
        float s[16];
        #pragma unroll
        for (int r = 0; r < 16; ++r)
            s[r] = fmaf(c[r], 0.125f, ((const float*)&b4[r >> 2])[r & 3]);
        float mx = s[0];
        #pragma unroll
        for (int r = 1; r < 16; ++r) mx = fmaxf(mx, s[r]);
        mx = fmaxf(mx, __shfl_xor(mx, 32));
        const bool upd = (mx > m_run + 8.f);   // defer-max (T13)
        if (__any(upd)) {
            float sc = 1.f;
            if (upd) { sc = __expf(m_run - mx); m_run = mx; }
            l_run *= sc;
            if (!hi) sc_l[w][q5] = sc;
            float4 scv[4];   // per-ROW scale: acc rows q(r) need sc[q(r)]
            #pragma unroll
            for (int g = 0; g < 4; ++g) scv[g] = *(const float4*)&sc_l[w][g * 8 + hi * 4];
            #pragma unroll
            for (int j = 0; j < 6; ++j)
                #pragma unroll
                for (int r = 0; r < 16; ++r) acc[j][r] *= ((const float*)&scv[r >> 2])[r & 3];
        }
        float p[16], ps = 0.f;
        #pragma unroll
        for (int r = 0; r < 16; ++r) { p[r] = __expf(s[r] - m_run); ps += p[r]; }
        ps += __shfl_xor(ps, 32);
        l_run += ps;
        // pack p -> PV A-frags in wave-private LDS (same-wave ordering, no barrier)
        #pragma unroll
        for (int j = 0; j < 8; ++j) {
            const int r = j * 2;
            const unsigned int pk = (unsigned int)f2bf(p[r]) | ((unsigned int)f2bf(p[r + 1]) << 16);
            const int m_ = r >> 3;
            const int lp = q5 + 32 * ((r >> 2) & 1);
            const int by = ((r & 3) + 4 * hi) * 2;
            *(unsigned int*)((char*)pw + m_ * 1024 + lp * 16 + by) = pk;
        }
        const short8 pf0 = *(const short8*)(pw + l * 8);
        const short8 pf1 = *(const short8*)(pw + 512 + l * 8);
        // PV: acc[j] += P[:,0:16] x xT[0:16,db] + P[:,16:32] x xT[16:32,db]
        #pragma unroll
        for (int j = 0; j < 6; ++j) {
            acc[j] = __builtin_amdgcn_mfma_f32_32x32x16_bf16(pf0, xv[j], acc[j], 0, 0, 0);
            acc[j] = __builtin_amdgcn_mfma_f32_32x32x16_bf16(pf1, xv[6 + j], acc[j], 0, 0, 0);
        }
    };

    for (int it = 0; it < NT; it += 2) {
        step(it, kfA, kfB);
        step(it + 1, kfB, kfA);
    }

    // ---------- epilogue: inv broadcast, q-mask, store ----------
    {
        const float mq = maskf[bS + q0 + q5];
        const float inv = (mq > 0.f && l_run > 0.f) ? (1.f / l_run) : 0.f;
        if (!hi) sc_l[w][q5] = inv;
        float4 iv[4];
        #pragma unroll
        for (int g = 0; g < 4; ++g) iv[g] = *(const float4*)&sc_l[w][g * 8 + hi * 4];
        #pragma unroll
        for (int j = 0; j < 6; ++j) {
            const int dcol = dg * 192 + j * 32 + q5;
            #pragma unroll
            for (int r = 0; r < 16; ++r) {
                const int qr = (r & 3) + 8 * (r >> 2) + 4 * hi;
                out[(size_t)(bS + q0 + qr) * D_ + dcol] = acc[j][r] * ((const float*)&iv[r >> 2])[r & 3];
            }
        }
    }
}

extern "C" void kernel_launch(void* const* d_in, const int* in_sizes, int n_in,
                              void* d_out, int out_size, void* d_ws, size_t ws_size,
                              hipStream_t stream) {
    const float*         x    = (const float*)d_in[0];
    const unsigned char* mraw = (const unsigned char*)d_in[1];
    const float*         Wq   = (const float*)d_in[2];
    const float*         Wk   = (const float*)d_in[3];
    float*               outp = (float*)d_out;

    // ws: maskf f32 | biasf f32 | qg bf16 | kg bf16 | xTg bf16  (~28.1 MB)
    float* maskf = (float*)d_ws;
    float* biasf = maskf + (size_t)B_ * S_;
    unsigned short* qg  = (unsigned short*)(biasf + (size_t)B_ * S_);
    unsigned short* kg  = qg + (size_t)B_ * S_ * U_;
    unsigned short* xTg = kg + (size_t)B_ * S_ * U_;

    decode_mask_k<<<(B_ * S_) / 256, 256, 0, stream>>>(mraw, maskf, biasf);
    proj_qk_k<<<(B_ * S_) / 16, 256, 0, stream>>>(x, Wq, Wk, qg, kg);
    xpose_k<<<B_ * (S_ / TK), 512, 0, stream>>>(x, xTg);
    attn_k<<<256, 512, 0, stream>>>(xTg, qg, kg, maskf, biasf, outp);
}